// Round 8
// baseline (526.326 us; speedup 1.0000x reference)
//
#include <hip/hip_runtime.h>

// Packed-sequence LSTM (B=4096, T=512, D=18, H=8) + Linear(8->1) head.
//
// R8 = R7 (producer/consumer wave split) + two fixes aimed at the measured
// 402cy/step vs ~140cy/step consumer issue gap:
//  1. Producer hand-pipelined: two named row buffers; row k+1's 5 LDS reads
//     issue BEFORE row k's FMAs (compiler then waits lgkmcnt(5), overlapping
//     ~120cy LDS latency with compute). R7's VGPR=68 proved no pipelining
//     happened -> ~1000cy/chunk of serial LDS stalls on the producer, making
//     it the barrier laggard.
//  2. Barrier every 16 steps (2-chunk windows) halves sync overhead.
//     Producer iter I: DMA chunks {2I+4,2I+5}, vmcnt(18), produce {2I+2,
//     2I+3}, lgkm(0), barrier. Consumer iter I: consume {2I,2I+1}, 16 steps,
//     batched stores, barrier. XG ring mod 4 stays reader/writer-disjoint in
//     all phases; consumer's first read of a window happens AFTER the
//     barrier (no cross-window prefetch -> no race with the producer's
//     concurrent window; costs one ~120cy stall per 16 steps).
// vmcnt proof (producer wave has NO stores -> pure load counting): at iter I
// wait, outstanding = {2I+2,2I+3} (18, issued iter I-1) + {2I+4,2I+5} (18,
// just issued) = 36; vmcnt(18) retires exactly {2I+2,2I+3}. Prologue: DMA
// {0..3} (36), vmcnt(18) retires {0,1}, produce {0,1}.

namespace {

constexpr int NT = 512;
constexpr int ND = 18;
constexpr float LOG2E = 1.4426950408889634f;

typedef float v2f __attribute__((ext_vector_type(2)));
typedef float v4f __attribute__((ext_vector_type(4)));

template <int C>
__device__ __forceinline__ float fdpp(float v) {
    const int i = __float_as_int(v);
    return __int_as_float(__builtin_amdgcn_update_dpp(i, i, C, 0xF, 0xF, true));
}
__device__ __forceinline__ void gload_lds(const void* g, void* l) {
    __builtin_amdgcn_global_load_lds(
        (const __attribute__((address_space(1))) void*)g,
        (__attribute__((address_space(3))) void*)l, 4, 0, 0);
}

__global__ __launch_bounds__(128, 1) void lstm_pc(
    const float* __restrict__ x, const int* __restrict__ lengths,
    const float* __restrict__ W_ih, const float* __restrict__ W_hh,
    const float* __restrict__ b_ih, const float* __restrict__ b_hh,
    const float* __restrict__ W_lin, const float* __restrict__ b_lin,
    float* __restrict__ out)
{
    // A ring: 32 row slots (row r -> slot r&31), [seq][elem0..15].
    // B ring: 4 chunk blocks, [row-in-chunk][seq][elem16..17].
    // XG ring: 4 chunk buffers, [t-in-chunk][gate-pair][seq(+1 pad)] of v2f.
    __shared__ __align__(16) float Aring[32][4][16];
    __shared__ __align__(16) float Bring[4][8][4][2];
    __shared__ __align__(16) v2f   XG[4][8][16][5];

    const int tid  = (int)threadIdx.x;
    const int wav  = tid >> 6;          // 0 = consumer, 1 = producer
    const int w    = tid & 63;
    const int grp  = w >> 4;            // seq within block
    const int l16  = w & 15;
    const int p    = l16 >> 3;          // half: 0 -> {i,g}, 1 -> {f,o}
    const int j    = l16 & 7;           // hidden unit
    const int lenmax = lengths[blockIdx.x * 4];       // sorted desc
    const int nwin = (lenmax + 15) >> 4;              // 16-step windows
    const int rowA = j + (p ? 8 : 0);   // p0: i, p1: f
    const int rowB = j + (p ? 24 : 16); // p0: g, p1: o

    if (wav == 1) {
        // ============================ PRODUCER ============================
        v2f wxA[9], wxB[9];
        {
            const v2f* ra = (const v2f*)(W_ih + rowA * ND);
            const v2f* rb = (const v2f*)(W_ih + rowB * ND);
#pragma unroll
            for (int k = 0; k < 9; ++k) { wxA[k] = ra[k]; wxB[k] = rb[k]; }
        }
        const float biasA = b_ih[rowA] + b_hh[rowA];
        const float biasB = b_ih[rowB] + b_hh[rowB];

        // DMA source lanes: A-op: seq w>>4, elem w&15 (row uniform).
        // B-op: row w>>3, seq (w>>1)&3, elem 16+(w&1); dest linear = lane.
        const char* xc = (const char*)x;
        const char* pA = xc + (size_t)((((unsigned)(blockIdx.x * 4 + (w >> 4)) * (NT * ND))
                                       + (unsigned)(w & 15)) * 4u);
        const char* pB = xc + (size_t)((((unsigned)(blockIdx.x * 4 + ((w >> 1) & 3)) * (NT * ND))
                                       + 16u + (unsigned)(w & 1)) * 4u);
        const unsigned rB0 = (unsigned)(w >> 3);

        auto dma_chunk = [&](int dd) {
            const int r0 = dd * 8;
#pragma unroll
            for (int k = 0; k < 8; ++k) {
                const int rr = (r0 + k < NT) ? (r0 + k) : (NT - 1);
                gload_lds(pA + (unsigned)rr * 72u, &Aring[(r0 + k) & 31][0][0]);
            }
            unsigned rb = (unsigned)r0 + rB0;
            rb = (rb < (unsigned)NT) ? rb : (unsigned)(NT - 1);
            gload_lds(pB + rb * 72u, &Bring[dd & 3][0][0][0]);
        };

        auto rowread = [&](v4f (&qa)[4], v2f& qb, int rr, int bf, int kk) {
            const v4f* ap = (const v4f*)&Aring[rr & 31][grp][0];
            qa[0] = ap[0]; qa[1] = ap[1]; qa[2] = ap[2]; qa[3] = ap[3];
            qb = *(const v2f*)&Bring[bf][kk][grp][0];
        };
        auto rowcomp = [&](const v4f (&qa)[4], const v2f& qb, int bf, int kk) {
            v2f aA = v2f{biasA, 0.f}, aB = v2f{biasB, 0.f};
            aA = qa[0].lo * wxA[0] + aA;  aB = qa[0].lo * wxB[0] + aB;
            aA = qa[0].hi * wxA[1] + aA;  aB = qa[0].hi * wxB[1] + aB;
            aA = qa[1].lo * wxA[2] + aA;  aB = qa[1].lo * wxB[2] + aB;
            aA = qa[1].hi * wxA[3] + aA;  aB = qa[1].hi * wxB[3] + aB;
            aA = qa[2].lo * wxA[4] + aA;  aB = qa[2].lo * wxB[4] + aB;
            aA = qa[2].hi * wxA[5] + aA;  aB = qa[2].hi * wxB[5] + aB;
            aA = qa[3].lo * wxA[6] + aA;  aB = qa[3].lo * wxB[6] + aB;
            aA = qa[3].hi * wxA[7] + aA;  aB = qa[3].hi * wxB[7] + aB;
            aA = qb * wxA[8] + aA;        aB = qb * wxB[8] + aB;
            XG[bf][kk][l16][grp] = v2f{aA.x + aA.y, aB.x + aB.y};
        };

        // Produce chunks {c0, c0+1} (16 rows), 1-row-ahead pipelined.
        auto produce_win = [&](int c0) {
            const int r0  = c0 * 8;
            const int bf0 = c0 & 3, bf1 = (c0 + 1) & 3;
            v4f qa[4], qb[4];
            v2f ba, bb;
            rowread(qa, ba, r0, bf0, 0);
#pragma unroll
            for (int k = 0; k < 16; k += 2) {
                if (k + 1 < 16)
                    rowread(qb, bb, r0 + k + 1, ((k + 1) < 8) ? bf0 : bf1, (k + 1) & 7);
                rowcomp(qa, ba, (k < 8) ? bf0 : bf1, k & 7);
                if (k + 2 < 16)
                    rowread(qa, ba, r0 + k + 2, ((k + 2) < 8) ? bf0 : bf1, (k + 2) & 7);
                if (k + 1 < 16)
                    rowcomp(qb, bb, ((k + 1) < 8) ? bf0 : bf1, (k + 1) & 7);
            }
        };

        // prologue: DMA chunks 0..3 (36 ops), produce window {0,1}
        dma_chunk(0); dma_chunk(1); dma_chunk(2); dma_chunk(3);
        asm volatile("s_waitcnt vmcnt(18)" ::: "memory");
        produce_win(0);
        asm volatile("s_waitcnt lgkmcnt(0)" ::: "memory");
        __builtin_amdgcn_sched_barrier(0);
        __builtin_amdgcn_s_barrier();
        __builtin_amdgcn_sched_barrier(0);

        for (int I = 0; I < nwin; ++I) {
            dma_chunk(2 * I + 4);
            dma_chunk(2 * I + 5);
            asm volatile("s_waitcnt vmcnt(18)" ::: "memory");
            produce_win(2 * I + 2);
            asm volatile("s_waitcnt lgkmcnt(0)" ::: "memory");
            __builtin_amdgcn_sched_barrier(0);
            __builtin_amdgcn_s_barrier();
            __builtin_amdgcn_sched_barrier(0);
        }
    } else {
        // ============================ CONSUMER ============================
        const int len = lengths[blockIdx.x * 4 + grp];

        // DPP self-calibration: which h-index does row_ror:r deliver here?
        int idx[8];
        idx[0] = j;
        idx[1] = __builtin_amdgcn_update_dpp(0, j, 0x121, 0xF, 0xF, true) & 7;
        idx[2] = __builtin_amdgcn_update_dpp(0, j, 0x122, 0xF, 0xF, true) & 7;
        idx[3] = __builtin_amdgcn_update_dpp(0, j, 0x123, 0xF, 0xF, true) & 7;
        idx[4] = __builtin_amdgcn_update_dpp(0, j, 0x124, 0xF, 0xF, true) & 7;
        idx[5] = __builtin_amdgcn_update_dpp(0, j, 0x125, 0xF, 0xF, true) & 7;
        idx[6] = __builtin_amdgcn_update_dpp(0, j, 0x126, 0xF, 0xF, true) & 7;
        idx[7] = __builtin_amdgcn_update_dpp(0, j, 0x127, 0xF, 0xF, true) & 7;

        v2f whA[4], whB[4], wl2[4];
#pragma unroll
        for (int r = 0; r < 4; ++r) {
            whA[r] = v2f{W_hh[rowA * 8 + idx[2 * r]], W_hh[rowA * 8 + idx[2 * r + 1]]};
            whB[r] = v2f{W_hh[rowB * 8 + idx[2 * r]], W_hh[rowB * 8 + idx[2 * r + 1]]};
            wl2[r] = v2f{W_lin[idx[2 * r]], W_lin[idx[2 * r + 1]]};
        }
        const float bl = b_lin[0];
        // vB exponent scale: p0 computes tanh(g)=2*sigma(2g)-1, p1 sigma(o)
        const float Kp = p ? -LOG2E : -2.0f * LOG2E;

        float* yb = out + (size_t)(blockIdx.x * 4 + grp) * NT;

        v2f hp[4] = {v2f{0.f, 0.f}, v2f{0.f, 0.f}, v2f{0.f, 0.f}, v2f{0.f, 0.f}};
        float c_ = 0.0f, hown = 0.0f;

        __builtin_amdgcn_s_barrier();           // pairs with producer prologue
        __builtin_amdgcn_sched_barrier(0);

        for (int I = 0; I < nwin; ++I) {
            const int t = I * 16;
            const v2f* xg0 = &XG[(2 * I) & 3][0][l16][grp];      // step stride 80 v2f
            const v2f* xg1 = &XG[(2 * I + 1) & 3][0][l16][grp];
            float y[16];
            v2f xgn = xg0[0];   // first read AFTER the barrier (no cross-window race)
#pragma unroll
            for (int k = 0; k < 16; ++k) {
                const v2f xgc = xgn;
                if (k < 15) xgn = (k + 1 < 8) ? xg0[(k + 1) * 80] : xg1[(k + 1 - 8) * 80];

                // recurrent dots
                v2f tA = hp[0] * whA[0];
                tA = hp[1] * whA[1] + tA;
                tA = hp[2] * whA[2] + tA;
                tA = hp[3] * whA[3] + tA;
                v2f tB = hp[0] * whB[0];
                tB = hp[1] * whB[1] + tB;
                tB = hp[2] * whB[2] + tB;
                tB = hp[3] * whB[3] + tB;
                const float aA = (xgc.x + tA.x) + tA.y;
                const float aB = (xgc.y + tB.x) + tB.y;

                // activations: vA = sigma(i|f); vB = p0 tanh(g), p1 sigma(o)
                const float vA = __builtin_amdgcn_rcpf(
                    1.0f + __builtin_amdgcn_exp2f(aA * -LOG2E));
                const float sB = __builtin_amdgcn_rcpf(
                    1.0f + __builtin_amdgcn_exp2f(aB * Kp));
                const float vB = p ? sB : fmaf(2.0f, sB, -1.0f);

                // half exchange via ror:8; unmasked cell update
                const float send1 = p ? vA : (vA * vB);
                const float ex1 = fdpp<0x128>(send1);
                const float f_ = p ? send1 : ex1;
                const float ig_ = p ? ex1 : send1;
                c_ = fmaf(f_, c_, ig_);
                const float tc = fmaf(-2.0f, __builtin_amdgcn_rcpf(
                    1.0f + __builtin_amdgcn_exp2f(c_ * (2.0f * LOG2E))), 1.0f);
                const float ex2 = fdpp<0x128>(vB);
                const float o_ = p ? vB : ex2;
                hown = o_ * tc;

                // h rotations -> pairs
                const float h1 = fdpp<0x121>(hown);
                const float h2 = fdpp<0x122>(hown);
                const float h3 = fdpp<0x123>(hown);
                const float h4 = fdpp<0x124>(hown);
                const float h5 = fdpp<0x125>(hown);
                const float h6 = fdpp<0x126>(hown);
                const float h7 = fdpp<0x127>(hown);
                hp[0] = v2f{hown, h1}; hp[1] = v2f{h2, h3};
                hp[2] = v2f{h4, h5};   hp[3] = v2f{h6, h7};

                // linear head (off the critical chain)
                v2f ya = hp[0] * wl2[0];
                ya = hp[1] * wl2[1] + ya;
                ya = hp[2] * wl2[2] + ya;
                ya = hp[3] * wl2[3] + ya;
                y[k] = (ya.x + ya.y) + bl;
            }

            if (l16 == 0) {
                if (t + 15 < len) {
                    *(v4f*)(yb + t)      = v4f{y[0],  y[1],  y[2],  y[3]};
                    *(v4f*)(yb + t + 4)  = v4f{y[4],  y[5],  y[6],  y[7]};
                    *(v4f*)(yb + t + 8)  = v4f{y[8],  y[9],  y[10], y[11]};
                    *(v4f*)(yb + t + 12) = v4f{y[12], y[13], y[14], y[15]};
                } else {
#pragma unroll
                    for (int k = 0; k < 16; ++k)
                        if (t + k < len) yb[t + k] = y[k];
                }
            }
            __builtin_amdgcn_sched_barrier(0);
            __builtin_amdgcn_s_barrier();
            __builtin_amdgcn_sched_barrier(0);
        }
    }
}

} // namespace

extern "C" void kernel_launch(void* const* d_in, const int* in_sizes, int n_in,
                              void* d_out, int out_size, void* d_ws, size_t ws_size,
                              hipStream_t stream) {
    const float* x     = (const float*)d_in[0];
    const int*   lens  = (const int*)d_in[1];
    const float* W_ih  = (const float*)d_in[2];
    const float* W_hh  = (const float*)d_in[3];
    const float* b_ih  = (const float*)d_in[4];
    const float* b_hh  = (const float*)d_in[5];
    const float* W_lin = (const float*)d_in[6];
    const float* b_lin = (const float*)d_in[7];
    float* out = (float*)d_out;

    // zero the padded region (kernel only writes t < len)
    hipMemsetAsync(out, 0, (size_t)4096 * NT * sizeof(float), stream);

    lstm_pc<<<1024, 128, 0, stream>>>(x, lens, W_ih, W_hh, b_ih, b_hh,
                                      W_lin, b_lin, out);
}

// Round 9
// 105.882 us; speedup vs baseline: 4.9709x; 4.9709x over previous
//
#include <hip/hip_runtime.h>

// Packed-sequence LSTM (B=4096, T=512, D=18, H=8) + Linear(8->1) head.
//
// R9 = R7 (best known: 85.7us, producer/consumer wave split, 8-step chunks)
// with exactly two deltas:
//  1. Producer software-pipelined with NAMED SCALARS (R8's array-through-
//     lambda version hit rule #20: runtime-indexed aggregates -> scratch;
//     WRITE_SIZE 4.2->19.5MB and 6x regression proved it). Row k+1's 5 LDS
//     reads (compile-time offsets off a per-chunk base) issue before row k's
//     FMAs, so ~120cy LDS latency overlaps compute instead of serializing
//     8x per chunk on the barrier-critical producer.
//  2. Consumer wave runs at s_setprio(1): genuine role-split (T5 prereq)
//     exists; when both waves share a SIMD the latency-critical consumer
//     wins issue arbitration.
//
// Structure recap (R7): block = 2 waves. Producer: LDS-DMA A/B rings with
// counted vmcnt (9 ops/chunk, wait vmcnt(9) retires chunk c+2 issued 2
// chunks ago), computes xg[t] = W_ih.x_t + bias 2 chunks ahead into XG ring.
// Consumer: serial LSTM, 1 ds_read_b64/step (prefetched 1 step ahead,
// boundary pair prefetched pre-barrier - writer of that buffer is 4 chunks
// away, no race), DPP-only cross-lane, raw s_barrier per chunk (NOT
// __syncthreads: that drains vmcnt and kills the DMA pipeline).

namespace {

constexpr int NT = 512;
constexpr int ND = 18;
constexpr float LOG2E = 1.4426950408889634f;

typedef float v2f __attribute__((ext_vector_type(2)));
typedef float v4f __attribute__((ext_vector_type(4)));

template <int C>
__device__ __forceinline__ float fdpp(float v) {
    const int i = __float_as_int(v);
    return __int_as_float(__builtin_amdgcn_update_dpp(i, i, C, 0xF, 0xF, true));
}
__device__ __forceinline__ void gload_lds(const void* g, void* l) {
    __builtin_amdgcn_global_load_lds(
        (const __attribute__((address_space(1))) void*)g,
        (__attribute__((address_space(3))) void*)l, 4, 0, 0);
}

__global__ __launch_bounds__(128, 1) void lstm_pc(
    const float* __restrict__ x, const int* __restrict__ lengths,
    const float* __restrict__ W_ih, const float* __restrict__ W_hh,
    const float* __restrict__ b_ih, const float* __restrict__ b_hh,
    const float* __restrict__ W_lin, const float* __restrict__ b_lin,
    float* __restrict__ out)
{
    // A ring: 32 row slots (row r -> slot r&31), [seq][elem0..15].
    // B ring: 4 chunk blocks, [row-in-chunk][seq][elem16..17].
    // XG ring: 4 chunk buffers, [t-in-chunk][gate-pair][seq(+1 pad)] of v2f.
    __shared__ __align__(16) float Aring[32][4][16];
    __shared__ __align__(16) float Bring[4][8][4][2];
    __shared__ __align__(16) v2f   XG[4][8][16][5];

    const int tid  = (int)threadIdx.x;
    const int wav  = tid >> 6;          // 0 = consumer, 1 = producer
    const int w    = tid & 63;
    const int grp  = w >> 4;            // seq within block
    const int l16  = w & 15;
    const int p    = l16 >> 3;          // half: 0 -> {i,g}, 1 -> {f,o}
    const int j    = l16 & 7;           // hidden unit
    const int lenmax = lengths[blockIdx.x * 4];       // sorted desc
    const int nch  = (lenmax + 7) >> 3;
    const int rowA = j + (p ? 8 : 0);   // p0: i, p1: f
    const int rowB = j + (p ? 24 : 16); // p0: g, p1: o

    if (wav == 1) {
        // ============================ PRODUCER ============================
        v2f wxA[9], wxB[9];
        {
            const v2f* ra = (const v2f*)(W_ih + rowA * ND);
            const v2f* rb = (const v2f*)(W_ih + rowB * ND);
#pragma unroll
            for (int k = 0; k < 9; ++k) { wxA[k] = ra[k]; wxB[k] = rb[k]; }
        }
        const float biasA = b_ih[rowA] + b_hh[rowA];
        const float biasB = b_ih[rowB] + b_hh[rowB];

        // DMA source lanes: A-op: seq w>>4, elem w&15 (row uniform).
        // B-op: row w>>3, seq (w>>1)&3, elem 16+(w&1); dest linear = lane.
        const char* xc = (const char*)x;
        const char* pA = xc + (size_t)((((unsigned)(blockIdx.x * 4 + (w >> 4)) * (NT * ND))
                                       + (unsigned)(w & 15)) * 4u);
        const char* pB = xc + (size_t)((((unsigned)(blockIdx.x * 4 + ((w >> 1) & 3)) * (NT * ND))
                                       + 16u + (unsigned)(w & 1)) * 4u);
        const unsigned rB0 = (unsigned)(w >> 3);

        auto dma_chunk = [&](int dd) {
            const int r0 = dd * 8;
#pragma unroll
            for (int k = 0; k < 8; ++k) {
                const int rr = (r0 + k < NT) ? (r0 + k) : (NT - 1);
                gload_lds(pA + (unsigned)rr * 72u, &Aring[(r0 + k) & 31][0][0]);
            }
            unsigned rb = (unsigned)r0 + rB0;
            rb = (rb < (unsigned)NT) ? rb : (unsigned)(NT - 1);
            gload_lds(pB + rb * 72u, &Bring[dd & 3][0][0][0]);
        };

        // Pipelined chunk production: named scalars only (rule #20), all LDS
        // offsets compile-time off per-chunk bases -> ds_read offset imms.
        auto produce_chunk = [&](int cc) {
            const int s0 = (cc * 8) & 31;
            const int bf = cc & 3;
            const v4f* ap  = (const v4f*)&Aring[s0][grp][0];   // +k -> +16 v4f
            const v2f* bp  = (const v2f*)&Bring[bf][0][grp][0];// +k -> +4 v2f
            v2f* xgw = &XG[bf][0][l16][grp];                   // +k -> +80 v2f

            v4f pa0, pa1, pa2, pa3, qa0, qa1, qa2, qa3;
            v2f pt, qt;

#define PR_A(KK) pa0 = ap[(KK)*16+0]; pa1 = ap[(KK)*16+1]; \
                 pa2 = ap[(KK)*16+2]; pa3 = ap[(KK)*16+3]; pt = bp[(KK)*4];
#define PR_B(KK) qa0 = ap[(KK)*16+0]; qa1 = ap[(KK)*16+1]; \
                 qa2 = ap[(KK)*16+2]; qa3 = ap[(KK)*16+3]; qt = bp[(KK)*4];
#define PC(A0, A1, A2, A3, TT, KK)                                    \
            {                                                         \
                v2f aA = v2f{biasA, 0.f}, aB = v2f{biasB, 0.f};       \
                aA = A0.lo * wxA[0] + aA;  aB = A0.lo * wxB[0] + aB;  \
                aA = A0.hi * wxA[1] + aA;  aB = A0.hi * wxB[1] + aB;  \
                aA = A1.lo * wxA[2] + aA;  aB = A1.lo * wxB[2] + aB;  \
                aA = A1.hi * wxA[3] + aA;  aB = A1.hi * wxB[3] + aB;  \
                aA = A2.lo * wxA[4] + aA;  aB = A2.lo * wxB[4] + aB;  \
                aA = A2.hi * wxA[5] + aA;  aB = A2.hi * wxB[5] + aB;  \
                aA = A3.lo * wxA[6] + aA;  aB = A3.lo * wxB[6] + aB;  \
                aA = A3.hi * wxA[7] + aA;  aB = A3.hi * wxB[7] + aB;  \
                aA = TT * wxA[8] + aA;     aB = TT * wxB[8] + aB;     \
                xgw[(KK) * 80] = v2f{aA.x + aA.y, aB.x + aB.y};       \
            }
            PR_A(0)
            PR_B(1) PC(pa0, pa1, pa2, pa3, pt, 0)
            PR_A(2) PC(qa0, qa1, qa2, qa3, qt, 1)
            PR_B(3) PC(pa0, pa1, pa2, pa3, pt, 2)
            PR_A(4) PC(qa0, qa1, qa2, qa3, qt, 3)
            PR_B(5) PC(pa0, pa1, pa2, pa3, pt, 4)
            PR_A(6) PC(qa0, qa1, qa2, qa3, qt, 5)
            PR_B(7) PC(pa0, pa1, pa2, pa3, pt, 6)
                    PC(qa0, qa1, qa2, qa3, qt, 7)
#undef PC
#undef PR_B
#undef PR_A
        };

        // prologue: DMA chunks 0..2 (27 ops), produce 0 and 1, DMA 3
        dma_chunk(0); dma_chunk(1); dma_chunk(2);
        asm volatile("s_waitcnt vmcnt(18)" ::: "memory");
        produce_chunk(0);
        asm volatile("s_waitcnt vmcnt(9)" ::: "memory");
        produce_chunk(1);
        dma_chunk(3);
        asm volatile("s_waitcnt lgkmcnt(0)" ::: "memory");
        __builtin_amdgcn_sched_barrier(0);
        __builtin_amdgcn_s_barrier();
        __builtin_amdgcn_sched_barrier(0);

        for (int c = 0; c < nch; ++c) {
            asm volatile("s_waitcnt vmcnt(9)" ::: "memory");
            dma_chunk(c + 4);
            produce_chunk(c + 2);
            asm volatile("s_waitcnt lgkmcnt(0)" ::: "memory");
            __builtin_amdgcn_sched_barrier(0);
            __builtin_amdgcn_s_barrier();
            __builtin_amdgcn_sched_barrier(0);
        }
    } else {
        // ============================ CONSUMER ============================
        const int len = lengths[blockIdx.x * 4 + grp];

        // DPP self-calibration: which h-index does row_ror:r deliver here?
        int idx[8];
        idx[0] = j;
        idx[1] = __builtin_amdgcn_update_dpp(0, j, 0x121, 0xF, 0xF, true) & 7;
        idx[2] = __builtin_amdgcn_update_dpp(0, j, 0x122, 0xF, 0xF, true) & 7;
        idx[3] = __builtin_amdgcn_update_dpp(0, j, 0x123, 0xF, 0xF, true) & 7;
        idx[4] = __builtin_amdgcn_update_dpp(0, j, 0x124, 0xF, 0xF, true) & 7;
        idx[5] = __builtin_amdgcn_update_dpp(0, j, 0x125, 0xF, 0xF, true) & 7;
        idx[6] = __builtin_amdgcn_update_dpp(0, j, 0x126, 0xF, 0xF, true) & 7;
        idx[7] = __builtin_amdgcn_update_dpp(0, j, 0x127, 0xF, 0xF, true) & 7;

        v2f whA[4], whB[4], wl2[4];
#pragma unroll
        for (int r = 0; r < 4; ++r) {
            whA[r] = v2f{W_hh[rowA * 8 + idx[2 * r]], W_hh[rowA * 8 + idx[2 * r + 1]]};
            whB[r] = v2f{W_hh[rowB * 8 + idx[2 * r]], W_hh[rowB * 8 + idx[2 * r + 1]]};
            wl2[r] = v2f{W_lin[idx[2 * r]], W_lin[idx[2 * r + 1]]};
        }
        const float bl = b_lin[0];
        // vB exponent scale: p0 computes tanh(g)=2*sigma(2g)-1, p1 sigma(o)
        const float Kp = p ? -LOG2E : -2.0f * LOG2E;

        float* yb = out + (size_t)(blockIdx.x * 4 + grp) * NT;

        v2f hp[4] = {v2f{0.f, 0.f}, v2f{0.f, 0.f}, v2f{0.f, 0.f}, v2f{0.f, 0.f}};
        float c_ = 0.0f, hown = 0.0f;

        __builtin_amdgcn_s_barrier();           // pairs with producer prologue
        __builtin_amdgcn_sched_barrier(0);
        __builtin_amdgcn_s_setprio(1);          // latency-critical wave wins
                                                // SIMD issue arbitration (T5)

        v2f xgn = XG[0][0][l16][grp];           // chunk 0, step 0 (pre-written)

        for (int c = 0; c < nch; ++c) {
            const v2f* xgp  = &XG[c & 3][0][l16][grp];       // t stride = 80 v2f
            const v2f* xgp1 = &XG[(c + 1) & 3][0][l16][grp];
            const int t = c * 8;
            float y[8];
#pragma unroll
            for (int k = 0; k < 8; ++k) {
                const v2f xgc = xgn;
                xgn = (k < 7) ? xgp[(k + 1) * 80] : xgp1[0];  // next-step prefetch

                // recurrent dots
                v2f tA = hp[0] * whA[0];
                tA = hp[1] * whA[1] + tA;
                tA = hp[2] * whA[2] + tA;
                tA = hp[3] * whA[3] + tA;
                v2f tB = hp[0] * whB[0];
                tB = hp[1] * whB[1] + tB;
                tB = hp[2] * whB[2] + tB;
                tB = hp[3] * whB[3] + tB;
                const float aA = (xgc.x + tA.x) + tA.y;
                const float aB = (xgc.y + tB.x) + tB.y;

                // activations: vA = sigma(i|f); vB = p0 tanh(g), p1 sigma(o)
                const float vA = __builtin_amdgcn_rcpf(
                    1.0f + __builtin_amdgcn_exp2f(aA * -LOG2E));
                const float sB = __builtin_amdgcn_rcpf(
                    1.0f + __builtin_amdgcn_exp2f(aB * Kp));
                const float vB = p ? sB : fmaf(2.0f, sB, -1.0f);

                // half exchange via ror:8; unmasked cell update
                const float send1 = p ? vA : (vA * vB);
                const float ex1 = fdpp<0x128>(send1);
                const float f_ = p ? send1 : ex1;
                const float ig_ = p ? ex1 : send1;
                c_ = fmaf(f_, c_, ig_);
                const float tc = fmaf(-2.0f, __builtin_amdgcn_rcpf(
                    1.0f + __builtin_amdgcn_exp2f(c_ * (2.0f * LOG2E))), 1.0f);
                const float ex2 = fdpp<0x128>(vB);
                const float o_ = p ? vB : ex2;
                hown = o_ * tc;

                // h rotations -> pairs
                const float h1 = fdpp<0x121>(hown);
                const float h2 = fdpp<0x122>(hown);
                const float h3 = fdpp<0x123>(hown);
                const float h4 = fdpp<0x124>(hown);
                const float h5 = fdpp<0x125>(hown);
                const float h6 = fdpp<0x126>(hown);
                const float h7 = fdpp<0x127>(hown);
                hp[0] = v2f{hown, h1}; hp[1] = v2f{h2, h3};
                hp[2] = v2f{h4, h5};   hp[3] = v2f{h6, h7};

                // linear head (off the critical chain)
                v2f ya = hp[0] * wl2[0];
                ya = hp[1] * wl2[1] + ya;
                ya = hp[2] * wl2[2] + ya;
                ya = hp[3] * wl2[3] + ya;
                y[k] = (ya.x + ya.y) + bl;
            }

            if (l16 == 0) {
                if (t + 7 < len) {
                    *(v4f*)(yb + t)     = v4f{y[0], y[1], y[2], y[3]};
                    *(v4f*)(yb + t + 4) = v4f{y[4], y[5], y[6], y[7]};
                } else {
                    if (t + 0 < len) yb[t + 0] = y[0];
                    if (t + 1 < len) yb[t + 1] = y[1];
                    if (t + 2 < len) yb[t + 2] = y[2];
                    if (t + 3 < len) yb[t + 3] = y[3];
                    if (t + 4 < len) yb[t + 4] = y[4];
                    if (t + 5 < len) yb[t + 5] = y[5];
                    if (t + 6 < len) yb[t + 6] = y[6];
                    if (t + 7 < len) yb[t + 7] = y[7];
                }
            }
            __builtin_amdgcn_sched_barrier(0);
            __builtin_amdgcn_s_barrier();
            __builtin_amdgcn_sched_barrier(0);
        }
    }
}

} // namespace

extern "C" void kernel_launch(void* const* d_in, const int* in_sizes, int n_in,
                              void* d_out, int out_size, void* d_ws, size_t ws_size,
                              hipStream_t stream) {
    const float* x     = (const float*)d_in[0];
    const int*   lens  = (const int*)d_in[1];
    const float* W_ih  = (const float*)d_in[2];
    const float* W_hh  = (const float*)d_in[3];
    const float* b_ih  = (const float*)d_in[4];
    const float* b_hh  = (const float*)d_in[5];
    const float* W_lin = (const float*)d_in[6];
    const float* b_lin = (const float*)d_in[7];
    float* out = (float*)d_out;

    // zero the padded region (kernel only writes t < len)
    hipMemsetAsync(out, 0, (size_t)4096 * NT * sizeof(float), stream);

    lstm_pc<<<1024, 128, 0, stream>>>(x, lens, W_ih, W_hh, b_ih, b_hh,
                                      W_lin, b_lin, out);
}

// Round 11
// 93.933 us; speedup vs baseline: 5.6032x; 1.1272x over previous
//
#include <hip/hip_runtime.h>

// Packed-sequence LSTM (B=4096, T=512, D=18, H=8) + Linear(8->1) head.
//
// R11 = R7 (proven best: 85.7us; producer/consumer wave split, 8-step
// chunks, counted vmcnt, raw s_barrier) with ONE mechanical change:
// all gate/head dot-products go through an inline-asm v_pk_fma_f32 helper.
// Evidence: R6/R7 issue-rate arithmetic showed the v2f expressions were
// scalarized (2x my packed estimate); both waves share SIMD issue, so
// halving FMA instruction count attacks the measured wall directly.
// R10's 2-producer split FAILED correctness (bug not found by audit) and is
// abandoned; R8/R9/R10 lesson: only locally-verifiable deltas off R7.
//
// Structure recap (R7): block = 2 waves. Producer (wave 1): LDS-DMA A/B
// rings, counted vmcnt (9 ops/chunk; vmcnt(9) retires chunk c+2 issued 2
// chunks ago), computes xg[t] = W_ih.x_t + bias 2 chunks ahead into a
// 4-buffer XG ring. Consumer (wave 0): serial LSTM, 1 ds_read_b64/step
// (prefetched 1 step ahead; boundary pair prefetched pre-barrier - its
// writer is 4 chunks away), DPP-only cross-lane (ror:8 gate exchange,
// ror:1..7 h-rotation with rotation-ordered weights via runtime DPP
// self-calibration), batched y stores, raw s_barrier per chunk (NOT
// __syncthreads: that drains vmcnt and kills the DMA pipeline).

namespace {

constexpr int NT = 512;
constexpr int ND = 18;
constexpr float LOG2E = 1.4426950408889634f;

typedef float v2f __attribute__((ext_vector_type(2)));
typedef float v4f __attribute__((ext_vector_type(4)));

template <int C>
__device__ __forceinline__ float fdpp(float v) {
    const int i = __float_as_int(v);
    return __int_as_float(__builtin_amdgcn_update_dpp(i, i, C, 0xF, 0xF, true));
}
__device__ __forceinline__ void gload_lds(const void* g, void* l) {
    __builtin_amdgcn_global_load_lds(
        (const __attribute__((address_space(1))) void*)g,
        (__attribute__((address_space(3))) void*)l, 4, 0, 0);
}
// Packed f32 FMA: d.lo = a.lo*b.lo + c.lo, d.hi = a.hi*b.hi + c.hi.
// (VOP3P default op_sel/op_sel_hi. Non-volatile -> freely schedulable.)
__device__ __forceinline__ v2f pkfma(v2f a, v2f b, v2f c) {
    v2f d;
    asm("v_pk_fma_f32 %0, %1, %2, %3" : "=v"(d) : "v"(a), "v"(b), "v"(c));
    return d;
}

__global__ __launch_bounds__(128, 1) void lstm_pc(
    const float* __restrict__ x, const int* __restrict__ lengths,
    const float* __restrict__ W_ih, const float* __restrict__ W_hh,
    const float* __restrict__ b_ih, const float* __restrict__ b_hh,
    const float* __restrict__ W_lin, const float* __restrict__ b_lin,
    float* __restrict__ out)
{
    // A ring: 32 row slots (row r -> slot r&31), [seq][elem0..15].
    // B ring: 4 chunk blocks, [row-in-chunk][seq][elem16..17].
    // XG ring: 4 chunk buffers, [t-in-chunk][gate-pair][seq(+1 pad)] of v2f.
    __shared__ __align__(16) float Aring[32][4][16];
    __shared__ __align__(16) float Bring[4][8][4][2];
    __shared__ __align__(16) v2f   XG[4][8][16][5];

    const int tid  = (int)threadIdx.x;
    const int wav  = tid >> 6;          // 0 = consumer, 1 = producer
    const int w    = tid & 63;
    const int grp  = w >> 4;            // seq within block
    const int l16  = w & 15;
    const int p    = l16 >> 3;          // half: 0 -> {i,g}, 1 -> {f,o}
    const int j    = l16 & 7;           // hidden unit
    const int lenmax = lengths[blockIdx.x * 4];       // sorted desc
    const int nch  = (lenmax + 7) >> 3;
    const int rowA = j + (p ? 8 : 0);   // p0: i, p1: f
    const int rowB = j + (p ? 24 : 16); // p0: g, p1: o

    if (wav == 1) {
        // ============================ PRODUCER ============================
        v2f wxA[9], wxB[9];
        {
            const v2f* ra = (const v2f*)(W_ih + rowA * ND);
            const v2f* rb = (const v2f*)(W_ih + rowB * ND);
#pragma unroll
            for (int k = 0; k < 9; ++k) { wxA[k] = ra[k]; wxB[k] = rb[k]; }
        }
        const float biasA = b_ih[rowA] + b_hh[rowA];
        const float biasB = b_ih[rowB] + b_hh[rowB];

        // DMA source lanes: A-op: seq w>>4, elem w&15 (row uniform).
        // B-op: row w>>3, seq (w>>1)&3, elem 16+(w&1); dest linear = lane.
        const char* xc = (const char*)x;
        const char* pA = xc + (size_t)((((unsigned)(blockIdx.x * 4 + (w >> 4)) * (NT * ND))
                                       + (unsigned)(w & 15)) * 4u);
        const char* pB = xc + (size_t)((((unsigned)(blockIdx.x * 4 + ((w >> 1) & 3)) * (NT * ND))
                                       + 16u + (unsigned)(w & 1)) * 4u);
        const unsigned rB0 = (unsigned)(w >> 3);

        auto dma_chunk = [&](int dd) {
            const int r0 = dd * 8;
#pragma unroll
            for (int k = 0; k < 8; ++k) {
                const int rr = (r0 + k < NT) ? (r0 + k) : (NT - 1);
                gload_lds(pA + (unsigned)rr * 72u, &Aring[(r0 + k) & 31][0][0]);
            }
            unsigned rb = (unsigned)r0 + rB0;
            rb = (rb < (unsigned)NT) ? rb : (unsigned)(NT - 1);
            gload_lds(pB + rb * 72u, &Bring[dd & 3][0][0][0]);
        };

        auto produce_chunk = [&](int cc) {
            const int s0 = (cc * 8) & 31;
            const int bf = cc & 3;
#pragma unroll
            for (int k = 0; k < 8; ++k) {
                const v4f* ap = (const v4f*)&Aring[s0 + k][grp][0];
                const v4f q0 = ap[0], q1 = ap[1], q2 = ap[2], q3 = ap[3];
                const v2f bt = *(const v2f*)&Bring[bf][k][grp][0];
                v2f aA = pkfma(q0.lo, wxA[0], v2f{biasA, 0.f});
                v2f aB = pkfma(q0.lo, wxB[0], v2f{biasB, 0.f});
                aA = pkfma(q0.hi, wxA[1], aA);  aB = pkfma(q0.hi, wxB[1], aB);
                aA = pkfma(q1.lo, wxA[2], aA);  aB = pkfma(q1.lo, wxB[2], aB);
                aA = pkfma(q1.hi, wxA[3], aA);  aB = pkfma(q1.hi, wxB[3], aB);
                aA = pkfma(q2.lo, wxA[4], aA);  aB = pkfma(q2.lo, wxB[4], aB);
                aA = pkfma(q2.hi, wxA[5], aA);  aB = pkfma(q2.hi, wxB[5], aB);
                aA = pkfma(q3.lo, wxA[6], aA);  aB = pkfma(q3.lo, wxB[6], aB);
                aA = pkfma(q3.hi, wxA[7], aA);  aB = pkfma(q3.hi, wxB[7], aB);
                aA = pkfma(bt,    wxA[8], aA);  aB = pkfma(bt,    wxB[8], aB);
                XG[bf][k][l16][grp] = v2f{aA.x + aA.y, aB.x + aB.y};
            }
        };

        // prologue: DMA chunks 0..2 (27 ops), produce 0 and 1, DMA 3
        dma_chunk(0); dma_chunk(1); dma_chunk(2);
        asm volatile("s_waitcnt vmcnt(18)" ::: "memory");
        produce_chunk(0);
        asm volatile("s_waitcnt vmcnt(9)" ::: "memory");
        produce_chunk(1);
        dma_chunk(3);
        asm volatile("s_waitcnt lgkmcnt(0)" ::: "memory");
        __builtin_amdgcn_sched_barrier(0);
        __builtin_amdgcn_s_barrier();
        __builtin_amdgcn_sched_barrier(0);

        for (int c = 0; c < nch; ++c) {
            asm volatile("s_waitcnt vmcnt(9)" ::: "memory");
            dma_chunk(c + 4);
            produce_chunk(c + 2);
            asm volatile("s_waitcnt lgkmcnt(0)" ::: "memory");
            __builtin_amdgcn_sched_barrier(0);
            __builtin_amdgcn_s_barrier();
            __builtin_amdgcn_sched_barrier(0);
        }
    } else {
        // ============================ CONSUMER ============================
        const int len = lengths[blockIdx.x * 4 + grp];

        // DPP self-calibration: which h-index does row_ror:r deliver here?
        int idx[8];
        idx[0] = j;
        idx[1] = __builtin_amdgcn_update_dpp(0, j, 0x121, 0xF, 0xF, true) & 7;
        idx[2] = __builtin_amdgcn_update_dpp(0, j, 0x122, 0xF, 0xF, true) & 7;
        idx[3] = __builtin_amdgcn_update_dpp(0, j, 0x123, 0xF, 0xF, true) & 7;
        idx[4] = __builtin_amdgcn_update_dpp(0, j, 0x124, 0xF, 0xF, true) & 7;
        idx[5] = __builtin_amdgcn_update_dpp(0, j, 0x125, 0xF, 0xF, true) & 7;
        idx[6] = __builtin_amdgcn_update_dpp(0, j, 0x126, 0xF, 0xF, true) & 7;
        idx[7] = __builtin_amdgcn_update_dpp(0, j, 0x127, 0xF, 0xF, true) & 7;

        v2f whA[4], whB[4], wl2[4];
#pragma unroll
        for (int r = 0; r < 4; ++r) {
            whA[r] = v2f{W_hh[rowA * 8 + idx[2 * r]], W_hh[rowA * 8 + idx[2 * r + 1]]};
            whB[r] = v2f{W_hh[rowB * 8 + idx[2 * r]], W_hh[rowB * 8 + idx[2 * r + 1]]};
            wl2[r] = v2f{W_lin[idx[2 * r]], W_lin[idx[2 * r + 1]]};
        }
        const float bl = b_lin[0];
        // vB exponent scale: p0 computes tanh(g)=2*sigma(2g)-1, p1 sigma(o)
        const float Kp = p ? -LOG2E : -2.0f * LOG2E;

        float* yb = out + (size_t)(blockIdx.x * 4 + grp) * NT;

        v2f hp[4] = {v2f{0.f, 0.f}, v2f{0.f, 0.f}, v2f{0.f, 0.f}, v2f{0.f, 0.f}};
        float c_ = 0.0f, hown = 0.0f;

        __builtin_amdgcn_s_barrier();           // pairs with producer prologue
        __builtin_amdgcn_sched_barrier(0);

        v2f xgn = XG[0][0][l16][grp];           // chunk 0, step 0 (pre-written)

        for (int c = 0; c < nch; ++c) {
            const v2f* xgp  = &XG[c & 3][0][l16][grp];       // t stride = 80 v2f
            const v2f* xgp1 = &XG[(c + 1) & 3][0][l16][grp];
            const int t = c * 8;
            float y[8];
#pragma unroll
            for (int k = 0; k < 8; ++k) {
                const v2f xgc = xgn;
                xgn = (k < 7) ? xgp[(k + 1) * 80] : xgp1[0];  // next-step prefetch

                // recurrent dots (packed; xg folded into the accumulator seed)
                v2f tA = pkfma(hp[0], whA[0], v2f{xgc.x, 0.f});
                tA = pkfma(hp[1], whA[1], tA);
                tA = pkfma(hp[2], whA[2], tA);
                tA = pkfma(hp[3], whA[3], tA);
                v2f tB = pkfma(hp[0], whB[0], v2f{xgc.y, 0.f});
                tB = pkfma(hp[1], whB[1], tB);
                tB = pkfma(hp[2], whB[2], tB);
                tB = pkfma(hp[3], whB[3], tB);
                const float aA = tA.x + tA.y;
                const float aB = tB.x + tB.y;

                // activations: vA = sigma(i|f); vB = p0 tanh(g), p1 sigma(o)
                const float vA = __builtin_amdgcn_rcpf(
                    1.0f + __builtin_amdgcn_exp2f(aA * -LOG2E));
                const float sB = __builtin_amdgcn_rcpf(
                    1.0f + __builtin_amdgcn_exp2f(aB * Kp));
                const float vB = p ? sB : fmaf(2.0f, sB, -1.0f);

                // half exchange via ror:8; unmasked cell update
                const float send1 = p ? vA : (vA * vB);
                const float ex1 = fdpp<0x128>(send1);
                const float f_ = p ? send1 : ex1;
                const float ig_ = p ? ex1 : send1;
                c_ = fmaf(f_, c_, ig_);
                const float tc = fmaf(-2.0f, __builtin_amdgcn_rcpf(
                    1.0f + __builtin_amdgcn_exp2f(c_ * (2.0f * LOG2E))), 1.0f);
                const float ex2 = fdpp<0x128>(vB);
                const float o_ = p ? vB : ex2;
                hown = o_ * tc;

                // h rotations -> pairs
                const float h1 = fdpp<0x121>(hown);
                const float h2 = fdpp<0x122>(hown);
                const float h3 = fdpp<0x123>(hown);
                const float h4 = fdpp<0x124>(hown);
                const float h5 = fdpp<0x125>(hown);
                const float h6 = fdpp<0x126>(hown);
                const float h7 = fdpp<0x127>(hown);
                hp[0] = v2f{hown, h1}; hp[1] = v2f{h2, h3};
                hp[2] = v2f{h4, h5};   hp[3] = v2f{h6, h7};

                // linear head (off the critical chain; packed)
                v2f ya = pkfma(hp[0], wl2[0], v2f{bl, 0.f});
                ya = pkfma(hp[1], wl2[1], ya);
                ya = pkfma(hp[2], wl2[2], ya);
                ya = pkfma(hp[3], wl2[3], ya);
                y[k] = ya.x + ya.y;
            }

            if (l16 == 0) {
                if (t + 7 < len) {
                    *(v4f*)(yb + t)     = v4f{y[0], y[1], y[2], y[3]};
                    *(v4f*)(yb + t + 4) = v4f{y[4], y[5], y[6], y[7]};
                } else {
                    if (t + 0 < len) yb[t + 0] = y[0];
                    if (t + 1 < len) yb[t + 1] = y[1];
                    if (t + 2 < len) yb[t + 2] = y[2];
                    if (t + 3 < len) yb[t + 3] = y[3];
                    if (t + 4 < len) yb[t + 4] = y[4];
                    if (t + 5 < len) yb[t + 5] = y[5];
                    if (t + 6 < len) yb[t + 6] = y[6];
                    if (t + 7 < len) yb[t + 7] = y[7];
                }
            }
            __builtin_amdgcn_sched_barrier(0);
            __builtin_amdgcn_s_barrier();
            __builtin_amdgcn_sched_barrier(0);
        }
    }
}

} // namespace

extern "C" void kernel_launch(void* const* d_in, const int* in_sizes, int n_in,
                              void* d_out, int out_size, void* d_ws, size_t ws_size,
                              hipStream_t stream) {
    const float* x     = (const float*)d_in[0];
    const int*   lens  = (const int*)d_in[1];
    const float* W_ih  = (const float*)d_in[2];
    const float* W_hh  = (const float*)d_in[3];
    const float* b_ih  = (const float*)d_in[4];
    const float* b_hh  = (const float*)d_in[5];
    const float* W_lin = (const float*)d_in[6];
    const float* b_lin = (const float*)d_in[7];
    float* out = (float*)d_out;

    // zero the padded region (kernel only writes t < len)
    hipMemsetAsync(out, 0, (size_t)4096 * NT * sizeof(float), stream);

    lstm_pc<<<1024, 128, 0, stream>>>(x, lens, W_ih, W_hh, b_ih, b_hh,
                                      W_lin, b_lin, out);
}

// Round 12
// 78.871 us; speedup vs baseline: 6.6733x; 1.1910x over previous
//
#include <hip/hip_runtime.h>

// Packed-sequence LSTM (B=4096, T=512, D=18, H=8) + Linear(8->1) head.
//
// R12 = R7 (proven best 85.7us) with pkfma REVERTED (R11: halving VALU
// instructions made the wall worse -> not issue-bound; compiler-scheduled
// v2f arithmetic restored verbatim) and ONE structural change:
//   Barrier every 16 steps (2 chunks) instead of every 8.
// Model from R7..R11: consumer chunk ~2300cy (chain), producer ~1500cy,
// wall 3200cy -> ~900cy/chunk is rendezvous overhead (skew + drains); the
// 4-buffer XG lead is wasted because the per-chunk barrier never lets the
// producer run ahead. Halving rendezvous count amortizes that overhead.
// The 16-step window structure itself was correctness-PROVEN in R8 (R8's
// regression was producer scratch, diagnosed and avoided here: producer
// keeps R7's plain compiler-scheduled loop).
//
// Producer window I: DMA chunks {2I+4,2I+5} (18 ops), vmcnt(18) retires
// {2I+2,2I+3} (issued one window ~4800cy ago >> 900cy HBM), produce both,
// lgkm(0), barrier. No stores on this wave -> vmcnt counts are exact.
// Ring safety: XG mod-4 writes {2I+2,2I+3} disjoint from consumer reads
// {2I,2I+1}; Aring DMA half [16I&31,+16) complementary to produce-read
// half [(16I+16)&31,+16); Bring buf (2I+4)&3 overwrites a chunk whose
// produce finished one window ago.
// Consumer window I: first xg read AFTER the barrier (its writer ran in
// the immediately-preceding window; pre-barrier prefetch would race) ->
// one ~120cy LDS stall per 16 steps; steps 1..15 prefetched 1 ahead.

namespace {

constexpr int NT = 512;
constexpr int ND = 18;
constexpr float LOG2E = 1.4426950408889634f;

typedef float v2f __attribute__((ext_vector_type(2)));
typedef float v4f __attribute__((ext_vector_type(4)));

template <int C>
__device__ __forceinline__ float fdpp(float v) {
    const int i = __float_as_int(v);
    return __int_as_float(__builtin_amdgcn_update_dpp(i, i, C, 0xF, 0xF, true));
}
__device__ __forceinline__ void gload_lds(const void* g, void* l) {
    __builtin_amdgcn_global_load_lds(
        (const __attribute__((address_space(1))) void*)g,
        (__attribute__((address_space(3))) void*)l, 4, 0, 0);
}

__global__ __launch_bounds__(128, 1) void lstm_pc(
    const float* __restrict__ x, const int* __restrict__ lengths,
    const float* __restrict__ W_ih, const float* __restrict__ W_hh,
    const float* __restrict__ b_ih, const float* __restrict__ b_hh,
    const float* __restrict__ W_lin, const float* __restrict__ b_lin,
    float* __restrict__ out)
{
    // A ring: 32 row slots (row r -> slot r&31), [seq][elem0..15].
    // B ring: 4 chunk blocks, [row-in-chunk][seq][elem16..17].
    // XG ring: 4 chunk buffers, [t-in-chunk][gate-pair][seq(+1 pad)] of v2f.
    __shared__ __align__(16) float Aring[32][4][16];
    __shared__ __align__(16) float Bring[4][8][4][2];
    __shared__ __align__(16) v2f   XG[4][8][16][5];

    const int tid  = (int)threadIdx.x;
    const int wav  = tid >> 6;          // 0 = consumer, 1 = producer
    const int w    = tid & 63;
    const int grp  = w >> 4;            // seq within block
    const int l16  = w & 15;
    const int p    = l16 >> 3;          // half: 0 -> {i,g}, 1 -> {f,o}
    const int j    = l16 & 7;           // hidden unit
    const int lenmax = lengths[blockIdx.x * 4];       // sorted desc
    const int nwin = (lenmax + 15) >> 4;              // 16-step windows
    const int rowA = j + (p ? 8 : 0);   // p0: i, p1: f
    const int rowB = j + (p ? 24 : 16); // p0: g, p1: o

    if (wav == 1) {
        // ============================ PRODUCER ============================
        v2f wxA[9], wxB[9];
        {
            const v2f* ra = (const v2f*)(W_ih + rowA * ND);
            const v2f* rb = (const v2f*)(W_ih + rowB * ND);
#pragma unroll
            for (int k = 0; k < 9; ++k) { wxA[k] = ra[k]; wxB[k] = rb[k]; }
        }
        const float biasA = b_ih[rowA] + b_hh[rowA];
        const float biasB = b_ih[rowB] + b_hh[rowB];

        // DMA source lanes: A-op: seq w>>4, elem w&15 (row uniform).
        // B-op: row w>>3, seq (w>>1)&3, elem 16+(w&1); dest linear = lane.
        const char* xc = (const char*)x;
        const char* pA = xc + (size_t)((((unsigned)(blockIdx.x * 4 + (w >> 4)) * (NT * ND))
                                       + (unsigned)(w & 15)) * 4u);
        const char* pB = xc + (size_t)((((unsigned)(blockIdx.x * 4 + ((w >> 1) & 3)) * (NT * ND))
                                       + 16u + (unsigned)(w & 1)) * 4u);
        const unsigned rB0 = (unsigned)(w >> 3);

        auto dma_chunk = [&](int dd) {
            const int r0 = dd * 8;
#pragma unroll
            for (int k = 0; k < 8; ++k) {
                const int rr = (r0 + k < NT) ? (r0 + k) : (NT - 1);
                gload_lds(pA + (unsigned)rr * 72u, &Aring[(r0 + k) & 31][0][0]);
            }
            unsigned rb = (unsigned)r0 + rB0;
            rb = (rb < (unsigned)NT) ? rb : (unsigned)(NT - 1);
            gload_lds(pB + rb * 72u, &Bring[dd & 3][0][0][0]);
        };

        // plain compiler-scheduled produce (R9/R11 lesson: don't hand-tune)
        auto produce_chunk = [&](int cc) {
            const int s0 = (cc * 8) & 31;
            const int bf = cc & 3;
#pragma unroll
            for (int k = 0; k < 8; ++k) {
                const v4f* ap = (const v4f*)&Aring[s0 + k][grp][0];
                const v4f q0 = ap[0], q1 = ap[1], q2 = ap[2], q3 = ap[3];
                const v2f bt = *(const v2f*)&Bring[bf][k][grp][0];
                v2f aA = v2f{biasA, 0.f}, aB = v2f{biasB, 0.f};
                aA = q0.lo * wxA[0] + aA;  aB = q0.lo * wxB[0] + aB;
                aA = q0.hi * wxA[1] + aA;  aB = q0.hi * wxB[1] + aB;
                aA = q1.lo * wxA[2] + aA;  aB = q1.lo * wxB[2] + aB;
                aA = q1.hi * wxA[3] + aA;  aB = q1.hi * wxB[3] + aB;
                aA = q2.lo * wxA[4] + aA;  aB = q2.lo * wxB[4] + aB;
                aA = q2.hi * wxA[5] + aA;  aB = q2.hi * wxB[5] + aB;
                aA = q3.lo * wxA[6] + aA;  aB = q3.lo * wxB[6] + aB;
                aA = q3.hi * wxA[7] + aA;  aB = q3.hi * wxB[7] + aB;
                aA = bt * wxA[8] + aA;     aB = bt * wxB[8] + aB;
                XG[bf][k][l16][grp] = v2f{aA.x + aA.y, aB.x + aB.y};
            }
        };

        // prologue: DMA chunks 0..3 (36 ops); {0,1} ready after vmcnt(18)
        dma_chunk(0); dma_chunk(1); dma_chunk(2); dma_chunk(3);
        asm volatile("s_waitcnt vmcnt(18)" ::: "memory");
        produce_chunk(0);
        produce_chunk(1);
        asm volatile("s_waitcnt lgkmcnt(0)" ::: "memory");
        __builtin_amdgcn_sched_barrier(0);
        __builtin_amdgcn_s_barrier();
        __builtin_amdgcn_sched_barrier(0);

        for (int I = 0; I < nwin; ++I) {
            dma_chunk(2 * I + 4);
            dma_chunk(2 * I + 5);
            asm volatile("s_waitcnt vmcnt(18)" ::: "memory");
            produce_chunk(2 * I + 2);
            produce_chunk(2 * I + 3);
            asm volatile("s_waitcnt lgkmcnt(0)" ::: "memory");
            __builtin_amdgcn_sched_barrier(0);
            __builtin_amdgcn_s_barrier();
            __builtin_amdgcn_sched_barrier(0);
        }
    } else {
        // ============================ CONSUMER ============================
        const int len = lengths[blockIdx.x * 4 + grp];

        // DPP self-calibration: which h-index does row_ror:r deliver here?
        int idx[8];
        idx[0] = j;
        idx[1] = __builtin_amdgcn_update_dpp(0, j, 0x121, 0xF, 0xF, true) & 7;
        idx[2] = __builtin_amdgcn_update_dpp(0, j, 0x122, 0xF, 0xF, true) & 7;
        idx[3] = __builtin_amdgcn_update_dpp(0, j, 0x123, 0xF, 0xF, true) & 7;
        idx[4] = __builtin_amdgcn_update_dpp(0, j, 0x124, 0xF, 0xF, true) & 7;
        idx[5] = __builtin_amdgcn_update_dpp(0, j, 0x125, 0xF, 0xF, true) & 7;
        idx[6] = __builtin_amdgcn_update_dpp(0, j, 0x126, 0xF, 0xF, true) & 7;
        idx[7] = __builtin_amdgcn_update_dpp(0, j, 0x127, 0xF, 0xF, true) & 7;

        v2f whA[4], whB[4], wl2[4];
#pragma unroll
        for (int r = 0; r < 4; ++r) {
            whA[r] = v2f{W_hh[rowA * 8 + idx[2 * r]], W_hh[rowA * 8 + idx[2 * r + 1]]};
            whB[r] = v2f{W_hh[rowB * 8 + idx[2 * r]], W_hh[rowB * 8 + idx[2 * r + 1]]};
            wl2[r] = v2f{W_lin[idx[2 * r]], W_lin[idx[2 * r + 1]]};
        }
        const float bl = b_lin[0];
        // vB exponent scale: p0 computes tanh(g)=2*sigma(2g)-1, p1 sigma(o)
        const float Kp = p ? -LOG2E : -2.0f * LOG2E;

        float* yb = out + (size_t)(blockIdx.x * 4 + grp) * NT;

        v2f hp[4] = {v2f{0.f, 0.f}, v2f{0.f, 0.f}, v2f{0.f, 0.f}, v2f{0.f, 0.f}};
        float c_ = 0.0f, hown = 0.0f;

        __builtin_amdgcn_s_barrier();           // pairs with producer prologue
        __builtin_amdgcn_sched_barrier(0);

        for (int I = 0; I < nwin; ++I) {
            const int t = I * 16;
            const v2f* xg0 = &XG[(2 * I) & 3][0][l16][grp];      // step stride 80 v2f
            const v2f* xg1 = &XG[(2 * I + 1) & 3][0][l16][grp];
            float y[16];
            v2f xgn = xg0[0];   // first read AFTER barrier (writer was last window)
#pragma unroll
            for (int k = 0; k < 16; ++k) {
                const v2f xgc = xgn;
                if (k < 15) xgn = (k + 1 < 8) ? xg0[(k + 1) * 80] : xg1[(k + 1 - 8) * 80];

                // recurrent dots
                v2f tA = hp[0] * whA[0];
                tA = hp[1] * whA[1] + tA;
                tA = hp[2] * whA[2] + tA;
                tA = hp[3] * whA[3] + tA;
                v2f tB = hp[0] * whB[0];
                tB = hp[1] * whB[1] + tB;
                tB = hp[2] * whB[2] + tB;
                tB = hp[3] * whB[3] + tB;
                const float aA = (xgc.x + tA.x) + tA.y;
                const float aB = (xgc.y + tB.x) + tB.y;

                // activations: vA = sigma(i|f); vB = p0 tanh(g), p1 sigma(o)
                const float vA = __builtin_amdgcn_rcpf(
                    1.0f + __builtin_amdgcn_exp2f(aA * -LOG2E));
                const float sB = __builtin_amdgcn_rcpf(
                    1.0f + __builtin_amdgcn_exp2f(aB * Kp));
                const float vB = p ? sB : fmaf(2.0f, sB, -1.0f);

                // half exchange via ror:8; unmasked cell update
                const float send1 = p ? vA : (vA * vB);
                const float ex1 = fdpp<0x128>(send1);
                const float f_ = p ? send1 : ex1;
                const float ig_ = p ? ex1 : send1;
                c_ = fmaf(f_, c_, ig_);
                const float tc = fmaf(-2.0f, __builtin_amdgcn_rcpf(
                    1.0f + __builtin_amdgcn_exp2f(c_ * (2.0f * LOG2E))), 1.0f);
                const float ex2 = fdpp<0x128>(vB);
                const float o_ = p ? vB : ex2;
                hown = o_ * tc;

                // h rotations -> pairs
                const float h1 = fdpp<0x121>(hown);
                const float h2 = fdpp<0x122>(hown);
                const float h3 = fdpp<0x123>(hown);
                const float h4 = fdpp<0x124>(hown);
                const float h5 = fdpp<0x125>(hown);
                const float h6 = fdpp<0x126>(hown);
                const float h7 = fdpp<0x127>(hown);
                hp[0] = v2f{hown, h1}; hp[1] = v2f{h2, h3};
                hp[2] = v2f{h4, h5};   hp[3] = v2f{h6, h7};

                // linear head (off the critical chain)
                v2f ya = hp[0] * wl2[0];
                ya = hp[1] * wl2[1] + ya;
                ya = hp[2] * wl2[2] + ya;
                ya = hp[3] * wl2[3] + ya;
                y[k] = (ya.x + ya.y) + bl;
            }

            if (l16 == 0) {
                if (t + 15 < len) {
                    *(v4f*)(yb + t)      = v4f{y[0],  y[1],  y[2],  y[3]};
                    *(v4f*)(yb + t + 4)  = v4f{y[4],  y[5],  y[6],  y[7]};
                    *(v4f*)(yb + t + 8)  = v4f{y[8],  y[9],  y[10], y[11]};
                    *(v4f*)(yb + t + 12) = v4f{y[12], y[13], y[14], y[15]};
                } else {
#pragma unroll
                    for (int k = 0; k < 16; ++k)
                        if (t + k < len) yb[t + k] = y[k];
                }
            }
            __builtin_amdgcn_sched_barrier(0);
            __builtin_amdgcn_s_barrier();
            __builtin_amdgcn_sched_barrier(0);
        }
    }
}

} // namespace

extern "C" void kernel_launch(void* const* d_in, const int* in_sizes, int n_in,
                              void* d_out, int out_size, void* d_ws, size_t ws_size,
                              hipStream_t stream) {
    const float* x     = (const float*)d_in[0];
    const int*   lens  = (const int*)d_in[1];
    const float* W_ih  = (const float*)d_in[2];
    const float* W_hh  = (const float*)d_in[3];
    const float* b_ih  = (const float*)d_in[4];
    const float* b_hh  = (const float*)d_in[5];
    const float* W_lin = (const float*)d_in[6];
    const float* b_lin = (const float*)d_in[7];
    float* out = (float*)d_out;

    // zero the padded region (kernel only writes t < len)
    hipMemsetAsync(out, 0, (size_t)4096 * NT * sizeof(float), stream);

    lstm_pc<<<1024, 128, 0, stream>>>(x, lens, W_ih, W_hh, b_ih, b_hh,
                                      W_lin, b_lin, out);
}